// Round 1
// baseline (43.100 us; speedup 1.0000x reference)
//
#include <hip/hip_runtime.h>

// Sigma = R * diag(exp(ls))^2 * R^T per gaussian.
// Memory-bound: 28 B in + 36 B out per gaussian, 4M gaussians = 256 MB.
// Strategy: 1 thread = 1 gaussian; LDS-stage the stride-3 input and stride-9
// output so all global traffic is coalesced float4.

constexpr int BLOCK = 256;

__global__ __launch_bounds__(BLOCK) void gauss_cov_kernel(
    const float4* __restrict__ rot,   // (N,4) quaternions, float4 per gaussian
    const float*  __restrict__ ls,    // (N,3) log scaling
    float*        __restrict__ out,   // (N,9) covariance
    int n)
{
    __shared__ float s_ls[BLOCK * 3];    // 3 KB
    __shared__ float s_out[BLOCK * 9];   // 9 KB

    const int t    = threadIdx.x;
    const int base = blockIdx.x * BLOCK;
    const int i    = base + t;
    const int cnt  = min(BLOCK, n - base);

    // ---- cooperative coalesced load of log_scaling (cnt*3 floats) ----
    {
        const float* g = ls + (size_t)base * 3;
        if (cnt == BLOCK) {
            // 768 floats = 192 float4; base*3*4 bytes is 16B-aligned (base%256==0)
            if (t < (BLOCK * 3) / 4)
                reinterpret_cast<float4*>(s_ls)[t] =
                    reinterpret_cast<const float4*>(g)[t];
        } else {
            for (int k = t; k < cnt * 3; k += BLOCK) s_ls[k] = g[k];
        }
    }
    __syncthreads();

    if (t < cnt) {
        const float4 q = rot[i];           // coalesced 16B/lane
        float w = q.x, x = q.y, y = q.z, z = q.w;
        const float nrm = sqrtf(w * w + x * x + y * y + z * z);
        const float inv = 1.0f / fmaxf(nrm, 1e-12f);
        w *= inv; x *= inv; y *= inv; z *= inv;

        const float sx = expf(s_ls[t * 3 + 0]);   // stride-3 LDS: <=2 lanes/bank, free
        const float sy = expf(s_ls[t * 3 + 1]);
        const float sz = expf(s_ls[t * 3 + 2]);

        // M = R * diag(s)
        const float m00 = (1.0f - 2.0f * (y * y + z * z)) * sx;
        const float m01 = (2.0f * (x * y - w * z)) * sy;
        const float m02 = (2.0f * (x * z + w * y)) * sz;
        const float m10 = (2.0f * (x * y + w * z)) * sx;
        const float m11 = (1.0f - 2.0f * (x * x + z * z)) * sy;
        const float m12 = (2.0f * (y * z - w * x)) * sz;
        const float m20 = (2.0f * (x * z - w * y)) * sx;
        const float m21 = (2.0f * (y * z + w * x)) * sy;
        const float m22 = (1.0f - 2.0f * (x * x + y * y)) * sz;

        // Sigma = M * M^T (symmetric)
        float* o = &s_out[t * 9];          // stride-9 LDS: <=2 lanes/bank, free
        const float s01 = m00 * m10 + m01 * m11 + m02 * m12;
        const float s02 = m00 * m20 + m01 * m21 + m02 * m22;
        const float s12 = m10 * m20 + m11 * m21 + m12 * m22;
        o[0] = m00 * m00 + m01 * m01 + m02 * m02;
        o[1] = s01;
        o[2] = s02;
        o[3] = s01;
        o[4] = m10 * m10 + m11 * m11 + m12 * m12;
        o[5] = s12;
        o[6] = s02;
        o[7] = s12;
        o[8] = m20 * m20 + m21 * m21 + m22 * m22;
    }
    __syncthreads();

    // ---- cooperative coalesced store (cnt*9 floats) ----
    {
        float* g = out + (size_t)base * 9;
        if (cnt == BLOCK) {
            // 2304 floats = 576 float4; base*9*4 bytes is 16B-aligned
            for (int k = t; k < (BLOCK * 9) / 4; k += BLOCK)
                reinterpret_cast<float4*>(g)[k] =
                    reinterpret_cast<const float4*>(s_out)[k];
        } else {
            for (int k = t; k < cnt * 9; k += BLOCK) g[k] = s_out[k];
        }
    }
}

extern "C" void kernel_launch(void* const* d_in, const int* in_sizes, int n_in,
                              void* d_out, int out_size, void* d_ws, size_t ws_size,
                              hipStream_t stream) {
    const float4* rot = (const float4*)d_in[0];   // (N,4) f32
    const float*  ls  = (const float*)d_in[1];    // (N,3) f32
    float*        out = (float*)d_out;            // (N,9) f32

    const int n = in_sizes[0] / 4;
    const int grid = (n + BLOCK - 1) / BLOCK;
    gauss_cov_kernel<<<grid, BLOCK, 0, stream>>>(rot, ls, out, n);
}